// Round 11
// baseline (349.875 us; speedup 1.0000x reference)
//
#include <hip/hip_runtime.h>

// Problem constants (from reference)
#define BB   32
#define CC   64
#define HH   224
#define WW   224
#define H2   226
#define W2   226
#define HID  8

constexpr unsigned NPLANE = BB * CC;      // 2048 planes
constexpr unsigned XHW    = HH * WW;      // 50176 floats / x plane
constexpr unsigned HW2    = H2 * W2;      // 51076 floats / out plane
constexpr unsigned NTOT   = NPLANE * HW2; // 104,603,648 out elements
constexpr unsigned NTOT4  = NTOT / 4;     // 26,150,912 f4 (div by 256)
constexpr unsigned NBORD  = NPLANE * HH;  // 458,752 per border

// ---------------------------------------------------------------------------
// DIAGNOSTIC copy: R1's pad_copy pattern dispatched at 2x work so it lands
// in rocprof's top-5 with full counters. Second pass rewrites identical
// values (deterministic). Flat f4 index over out; ring -> 0.
// ---------------------------------------------------------------------------
__global__ __launch_bounds__(256) void copy2_k(const float* __restrict__ x,
                                               float* __restrict__ out) {
    const unsigned tid = blockIdx.x * 256u + threadIdx.x;   // < 2*NTOT4
    const unsigned i   = (tid >= NTOT4) ? (tid - NTOT4) : tid;
    const unsigned e   = i * 4u;
    const unsigned w0  = e % W2;
    const unsigned t0  = e / W2;
    const unsigned h0  = t0 % H2;
    const unsigned bc  = t0 / H2;
    float v[4];
    unsigned w = w0, h = h0, b = bc;
#pragma unroll
    for (int j = 0; j < 4; ++j) {
        unsigned hi = h - 1u;  // wraps huge if h==0
        unsigned wi = w - 1u;
        v[j] = (hi < (unsigned)HH && wi < (unsigned)WW)
                   ? x[b * XHW + hi * (unsigned)WW + wi]
                   : 0.f;
        ++w;
        if (w == W2) { w = 0; ++h; if (h == H2) { h = 0; ++b; } }
    }
    reinterpret_cast<float4*>(out)[i] = make_float4(v[0], v[1], v[2], v[3]);
}

// ---------------------------------------------------------------------------
// MLP: s[2][3] -> scalar. W layout: [w1 48][b1 8][w2 64][b2 8][w3 8][b3 1]
// ---------------------------------------------------------------------------
__device__ __forceinline__ float mlp_eval(const float s[2][3],
                                          const float* __restrict__ W) {
    const float* W1  = W;
    const float* B1  = W + 48;
    const float* W2m = W + 56;
    const float* B2  = W + 120;
    const float* W3  = W + 128;
    const float  b3  = W[136];
    float y1[HID];
#pragma unroll
    for (int h = 0; h < HID; ++h) {
        float a = B1[h];
#pragma unroll
        for (int r = 0; r < 2; ++r)
#pragma unroll
            for (int k = 0; k < 3; ++k)
                a = fmaf(s[r][k], W1[h * 6 + r * 3 + k], a);
        y1[h] = fmaxf(a, 0.f);
    }
    float y2[HID];
#pragma unroll
    for (int o = 0; o < HID; ++o) {
        float a = B2[o];
#pragma unroll
        for (int h = 0; h < HID; ++h) a = fmaf(y1[h], W2m[o * 8 + h], a);
        y2[o] = fmaxf(a, 0.f);
    }
    float a = b3;
#pragma unroll
    for (int h = 0; h < HID; ++h) a = fmaf(y2[h], W3[h], a);
    return fmaxf(a, 0.f);
}

__device__ __forceinline__ void load_wts(unsigned t, float* W,
                                         const float* w1, const float* b1,
                                         const float* w2, const float* b2,
                                         const float* w3, const float* b3) {
    if (t < 48u) W[t] = w1[t];
    if (t < 64u) W[56u + t] = w2[t];
    if (t < 8u) {
        W[48u + t]  = b1[t];
        W[120u + t] = b2[t];
        W[128u + t] = w3[t];
    }
    if (t == 0u) W[136] = b3[0];
}

// ---------------------------------------------------------------------------
// Top/bottom borders (proven-cheap R1 version).
// ---------------------------------------------------------------------------
__global__ __launch_bounds__(256) void border_tb_k(
    const float* __restrict__ x, float* __restrict__ out,
    const float* tw1, const float* tb1, const float* tw2, const float* tb2,
    const float* tw3, const float* tb3,
    const float* bw1, const float* bb1, const float* bw2, const float* bb2,
    const float* bw3, const float* bb3) {
    const bool top = (blockIdx.y == 0);
    __shared__ float W[137];
    load_wts(threadIdx.x, W,
             top ? tw1 : bw1, top ? tb1 : bb1, top ? tw2 : bw2,
             top ? tb2 : bb2, top ? tw3 : bw3, top ? tb3 : bb3);
    __syncthreads();

    const unsigned gid = blockIdx.x * 256u + threadIdx.x;
    const unsigned l   = gid % (unsigned)HH;
    const unsigned bc  = gid / (unsigned)HH;

    const unsigned r0 = top ? 0u : (unsigned)(HH - 2);
    float s[2][3];
#pragma unroll
    for (int r = 0; r < 2; ++r)
#pragma unroll
        for (int k = 0; k < 3; ++k) {
            unsigned xc = l + (unsigned)k - 1u;  // wrap-huge if OOB
            s[r][k] = (xc < (unsigned)WW)
                          ? x[bc * XHW + (r0 + (unsigned)r) * (unsigned)WW + xc]
                          : 0.f;
        }
    const float res = mlp_eval(s, W);
    const unsigned orow = top ? 0u : (unsigned)(H2 - 1);
    out[bc * HW2 + orow * (unsigned)W2 + (l + 1u)] = res;
}

// ---------------------------------------------------------------------------
// Left/right borders (proven-cheap R1 version; reads tb results from out).
// ---------------------------------------------------------------------------
__global__ __launch_bounds__(256) void border_lr_k(
    const float* __restrict__ x, float* __restrict__ out,
    const float* lw1, const float* lb1, const float* lw2, const float* lb2,
    const float* lw3, const float* lb3,
    const float* rw1, const float* rb1, const float* rw2, const float* rb2,
    const float* rw3, const float* rb3) {
    const bool left = (blockIdx.y == 0);
    __shared__ float W[137];
    load_wts(threadIdx.x, W,
             left ? lw1 : rw1, left ? lb1 : rb1, left ? lw2 : rw2,
             left ? lb2 : rb2, left ? lw3 : rw3, left ? lb3 : rb3);
    __syncthreads();

    const unsigned gid = blockIdx.x * 256u + threadIdx.x;
    const unsigned l   = gid % (unsigned)HH;  // writes padded row l+1
    const unsigned bc  = gid / (unsigned)HH;

    const unsigned cc0 = left ? 0u : (unsigned)(WW - 2);  // x col base
    const unsigned oc0 = left ? 1u : (unsigned)(W2 - 3);  // out col base (rows 0/225)
    float s[2][3];
#pragma unroll
    for (int k = 0; k < 3; ++k) {
        const unsigned pr = l + (unsigned)k;  // padded row l..l+2
        float v0, v1;
        if (pr == 0u) {
            v0 = out[bc * HW2 + oc0];
            v1 = out[bc * HW2 + oc0 + 1u];
        } else if (pr == (unsigned)(H2 - 1)) {
            v0 = out[bc * HW2 + (unsigned)(H2 - 1) * W2 + oc0];
            v1 = out[bc * HW2 + (unsigned)(H2 - 1) * W2 + oc0 + 1u];
        } else {
            const float2 t2 = *reinterpret_cast<const float2*>(
                x + bc * XHW + (pr - 1u) * (unsigned)WW + cc0);
            v0 = t2.x;
            v1 = t2.y;
        }
        s[0][k] = v0;
        s[1][k] = v1;
    }
    const float res = mlp_eval(s, W);
    out[bc * HW2 + (l + 1u) * (unsigned)W2 + (left ? 0u : (unsigned)(W2 - 1))] = res;
}

// ---------------------------------------------------------------------------
extern "C" void kernel_launch(void* const* d_in, const int* in_sizes, int n_in,
                              void* d_out, int out_size, void* d_ws,
                              size_t ws_size, hipStream_t stream) {
    const float* x = (const float*)d_in[0];
    const float* w[24];
    for (int i = 0; i < 24; ++i) w[i] = (const float*)d_in[1 + i];
    float* out = (float*)d_out;

    // 1) DIAGNOSTIC: padded copy at 2x work (second half idempotent) so the
    //    copy dispatch surfaces in rocprof top-5 with full counters.
    copy2_k<<<dim3(2u * (NTOT4 / 256u)), dim3(256), 0, stream>>>(x, out);

    // 2) top + bottom borders
    border_tb_k<<<dim3(NBORD / 256u, 2), dim3(256), 0, stream>>>(
        x, out, w[0], w[1], w[2], w[3], w[4], w[5],
        w[6], w[7], w[8], w[9], w[10], w[11]);

    // 3) left + right borders
    border_lr_k<<<dim3(NBORD / 256u, 2), dim3(256), 0, stream>>>(
        x, out, w[12], w[13], w[14], w[15], w[16], w[17],
        w[18], w[19], w[20], w[21], w[22], w[23]);
}